// Round 2
// baseline (176.416 us; speedup 1.0000x reference)
//
#include <hip/hip_runtime.h>
#include <stdint.h>

#define B 8
#define F 8192
#define C 256
#define K 4
#define P (F / 4)     // 2048
#define CAP 16        // max tracked incoming collapsed faces per target
#define NB 4096       // linear bins over per-batch [lo, hi]
#define CAND_CAP 8184 // LDS candidate capacity (bin==T population; ~7 typical)

// Monotone, deterministic linear bin.
__device__ __forceinline__ int binOf(float v, float lo, float scale) {
    int bin = (int)((v - lo) * scale);
    return bin < 0 ? 0 : (bin > NB - 1 ? NB - 1 : bin);
}

// ---------------------------------------------------------------------------
// kW: one wave per face — gather K=4 ring rows, mean, L2 norm -> w.
// Lane 0 zeroes cnt/flag. Block->batch swizzle: blockIdx&7 = batch, so each
// XCD's L2 serves ONE batch's 8 MB feat slice instead of all 64 MB.
// (unchanged — not the lever under test)
// ---------------------------------------------------------------------------
__global__ __launch_bounds__(256) void kW(const float* __restrict__ feat,
                                          const int* __restrict__ ring,
                                          float* __restrict__ w,
                                          int* __restrict__ cnt,
                                          int* __restrict__ flag) {
    const int b     = blockIdx.x & 7;                       // batch == XCD
    const int inner = blockIdx.x >> 3;                      // [0, 2048)
    const int wid   = b * F + inner * 4 + (threadIdx.x >> 6);
    const int lane  = threadIdx.x & 63;

    const int rbase = wid * K;
    const int r0 = ring[rbase + 0], r1 = ring[rbase + 1];
    const int r2 = ring[rbase + 2], r3 = ring[rbase + 3];
    const float4* f4 = (const float4*)feat;
    const size_t base = (size_t)b * F;
    const int    CW   = C / 4;
    const float4 v0 = f4[(base + r0) * CW + lane];
    const float4 v1 = f4[(base + r1) * CW + lane];
    const float4 v2 = f4[(base + r2) * CW + lane];
    const float4 v3 = f4[(base + r3) * CW + lane];

    float4 a;
    a.x = (v0.x + v1.x) + (v2.x + v3.x);
    a.y = (v0.y + v1.y) + (v2.y + v3.y);
    a.z = (v0.z + v1.z) + (v2.z + v3.z);
    a.w = (v0.w + v1.w) + (v2.w + v3.w);
    float s = (a.x * a.x + a.y * a.y + a.z * a.z + a.w * a.w) * 0.0625f;
#pragma unroll
    for (int off = 32; off > 0; off >>= 1) s += __shfl_down(s, off, 64);
    if (lane == 0) {
        w[wid]    = sqrtf(s);
        cnt[wid]  = 0;
        flag[wid] = 0;
    }
}

// ---------------------------------------------------------------------------
// kMid: fused kHT+kFL+kSel — ONE block per batch (8 x 1024), block-local only.
//   Phase HT : min/max + 4096-bin histogram + scan -> threshold bin T, rank R.
//   Phase FL : each thread re-uses its 8 w-values from registers; bin<T ->
//              flag + push into 3 adjacency lists; bin==T -> LDS candidate.
//   Phase Sel: exact rank of the ~7 boundary candidates from LDS; rank<R ->
//              flag + push.
// No grid sync, no global cand/ccnt round-trip. LDS union <= 64 KiB.
// ---------------------------------------------------------------------------
struct SMemHT { int h[NB]; unsigned int red[1024]; };        // 20 KiB
struct SMemFS { unsigned long long keys[CAND_CAP]; int lcnt; }; // ~64 KiB
union  SMemU  { SMemHT ht; SMemFS fs; };

__global__ __launch_bounds__(1024) void kMid(const float* __restrict__ w,
                                             const int* __restrict__ adj,
                                             int* __restrict__ flag,
                                             int* __restrict__ cnt,
                                             int* __restrict__ srcs) {
    __shared__ SMemU sm;
    __shared__ int sT, sR;
    const int b = blockIdx.x;
    const int t = threadIdx.x;

    // lcnt lives at byte ~65k of the union — untouched by ht.h/ht.red, so it
    // can be initialized here and is covered by the first __syncthreads below.
    if (t == 0) sm.fs.lcnt = 0;

    // ---- load w (8/thread, coalesced) + per-thread min/max ----
    float val[8];
    unsigned int mn = 0xFFFFFFFFu, mx = 0u;
#pragma unroll
    for (int k = 0; k < 8; ++k) {
        val[k] = w[b * F + t + k * 1024];
        const unsigned int u = __float_as_uint(val[k]);      // w>=0: bit-monotone
        mn = mn < u ? mn : u;
        mx = mx > u ? mx : u;
    }
    sm.ht.red[t] = mn;
    __syncthreads();
    for (int off = 512; off > 0; off >>= 1) {
        if (t < off) sm.ht.red[t] = min(sm.ht.red[t], sm.ht.red[t + off]);
        __syncthreads();
    }
    const unsigned int lob = sm.ht.red[0];
    __syncthreads();
    sm.ht.red[t] = mx;
    __syncthreads();
    for (int off = 512; off > 0; off >>= 1) {
        if (t < off) sm.ht.red[t] = max(sm.ht.red[t], sm.ht.red[t + off]);
        __syncthreads();
    }
    const unsigned int hib = sm.ht.red[0];
    __syncthreads();

    const float lo    = __uint_as_float(lob);
    const float hi    = __uint_as_float(hib);
    const float scale = (float)(NB - 2) / fmaxf(hi - lo, 1e-30f);

    // ---- histogram ----
    for (int i = t; i < NB; i += 1024) sm.ht.h[i] = 0;
    __syncthreads();
#pragma unroll
    for (int k = 0; k < 8; ++k) atomicAdd(&sm.ht.h[binOf(val[k], lo, scale)], 1);
    __syncthreads();

    // ---- inclusive scan over 1024 partials (4 bins/thread) -> T, R ----
    int s = 0;
#pragma unroll
    for (int i = 0; i < 4; ++i) s += sm.ht.h[t * 4 + i];
    int* part = (int*)sm.ht.red;
    part[t] = s;
    __syncthreads();
    for (int off = 1; off < 1024; off <<= 1) {
        const int v = part[t];
        const int u = (t >= off) ? part[t - off] : 0;
        __syncthreads();
        part[t] = v + u;
        __syncthreads();
    }
    const int excl = (t == 0) ? 0 : part[t - 1];
    if (P - 1 >= excl && P - 1 < part[t]) {                  // exactly one thread
        int c = excl;
#pragma unroll
        for (int i = 0; i < 4; ++i) {
            const int bin = t * 4 + i;
            const int hv  = sm.ht.h[bin];
            if (P - 1 < c + hv) { sT = bin; sR = P - c; break; }
            c += hv;
        }
    }
    __syncthreads();   // sT/sR visible; all done reading h -> union reusable

    // ---- Phase FL: flag+push definite collapses; compact boundary bin ----
    const int T = sT;
#pragma unroll
    for (int k = 0; k < 8; ++k) {
        const int face = b * F + t + k * 1024;
        const int bin  = binOf(val[k], lo, scale);
        if (bin < T) {
            flag[face] = 1;
#pragma unroll
            for (int j = 0; j < 3; ++j) {
                const int n    = adj[(size_t)face * 3 + j];
                const int tgt  = b * F + n;
                const int slot = atomicAdd(&cnt[tgt], 1);
                if (slot < CAP) srcs[(size_t)tgt * CAP + slot] = face;
            }
        } else if (bin == T) {
            const int pos = atomicAdd(&sm.fs.lcnt, 1);       // LDS atomic: cheap
            if (pos < CAND_CAP)
                sm.fs.keys[pos] = ((unsigned long long)__float_as_uint(val[k]) << 32) |
                                  (uint32_t)(face & (F - 1));
        }
    }
    __syncthreads();

    // ---- Phase Sel: exact rank of boundary candidates (n ~ 7) ----
    const int n = sm.fs.lcnt < CAND_CAP ? sm.fs.lcnt : CAND_CAP;
    const int R = sR;
    for (int i = t; i < n; i += 1024) {
        const unsigned long long my = sm.fs.keys[i];
        int rank = 0;
        for (int j = 0; j < n; ++j) rank += (sm.fs.keys[j] < my) ? 1 : 0;
        if (rank < R) {
            const int tt = b * F + (int)(uint32_t)my;
            flag[tt] = 1;
#pragma unroll
            for (int j = 0; j < 3; ++j) {
                const int nb   = adj[(size_t)tt * 3 + j];
                const int tgt  = b * F + nb;
                const int slot = atomicAdd(&cnt[tgt], 1);
                if (slot < CAP) srcs[(size_t)tgt * CAP + slot] = tt;
            }
        }
    }
}

// ---------------------------------------------------------------------------
// kG: one wave per face — fused merge + normalize + erase, same batch<->XCD
// swizzle as kW (incoming-src gathers are batch-local). (unchanged)
// ---------------------------------------------------------------------------
__global__ __launch_bounds__(256) void kG(const float* __restrict__ feat,
                                          const int* __restrict__ cnt,
                                          const int* __restrict__ flag,
                                          const int* __restrict__ srcs,
                                          float* __restrict__ out) {
    const int b     = blockIdx.x & 7;                       // batch == XCD
    const int inner = blockIdx.x >> 3;
    const int wid   = b * F + inner * 4 + (threadIdx.x >> 6);
    const int lane  = threadIdx.x & 63;
    float4* drow = (float4*)(out + (size_t)wid * C);

    if (flag[wid]) {                                        // wave-uniform branch
        drow[lane] = make_float4(0.f, 0.f, 0.f, 0.f);
        return;
    }
    const int m  = cnt[wid];
    const int mm = m < CAP ? m : CAP;

    const int sidx = (lane < CAP) ? srcs[(size_t)wid * CAP + lane] : 0;

    float4 acc = ((const float4*)(feat + (size_t)wid * C))[lane];
    const float inv3 = 1.0f / 3.0f;
    for (int i = 0; i < mm; ++i) {
        const int s = __shfl(sidx, i, 64);
        const float4 v = ((const float4*)(feat + (size_t)s * C))[lane];
        acc.x += v.x * inv3; acc.y += v.y * inv3;
        acc.z += v.z * inv3; acc.w += v.w * inv3;
    }
    const float inv = 1.0f / (1.0f + (float)m);
    acc.x *= inv; acc.y *= inv; acc.z *= inv; acc.w *= inv;
    drow[lane] = acc;
}

extern "C" void kernel_launch(void* const* d_in, const int* in_sizes, int n_in,
                              void* d_out, int out_size, void* d_ws, size_t ws_size,
                              hipStream_t stream) {
    const float* feat = (const float*)d_in[0];
    const int*   adj  = (const int*)d_in[1];
    const int*   ring = (const int*)d_in[2];
    float* out = (float*)d_out;

    // ws layout: w | cnt | flag | srcs
    float* w    = (float*)d_ws;                             // B*F
    int*   cnt  = (int*)(w + B * F);                        // B*F
    int*   flag = cnt + B * F;                              // B*F
    int*   srcs = flag + B * F;                             // B*F*CAP (4 MiB)

    kW  <<<(B * F) / 4, 256, 0, stream>>>(feat, ring, w, cnt, flag);
    kMid<<<B, 1024, 0, stream>>>(w, adj, flag, cnt, srcs);
    kG  <<<(B * F) / 4, 256, 0, stream>>>(feat, cnt, flag, srcs, out);
}